// Round 1
// baseline (129.538 us; speedup 1.0000x reference)
//
#include <hip/hip_runtime.h>
#include <math.h>

// Reference: sequential scan over T timesteps of independent per-synapse ODEs.
// Each thread owns 4 consecutive synapses (float4 columns), carries all live
// state in registers, streams the 4 used input rows (pre, post, post_v, reward)
// and writes the current row. pre_voltage and astro_mod are dead inputs.

namespace {

constexpr float TAU_GABA_A = 10.0f, TAU_GABA_B = 150.0f;
constexpr float TAU_D = 200.0f, TAU_ACH = 150.0f, TAU_NE = 100.0f, TAU_CA = 800.0f;
constexpr float ALPHA_D = 0.8f, BETA_ACH = 0.5f, GAMMA_NE = 0.3f;
constexpr float ALPHA_CA = 0.03f, BETA_ASTRO = 0.3f;
constexpr float TRACE_DECAY = 0.95f, BASE_LR = 0.01f;
constexpr float W_MIN = 0.001f, W_MAX = 1.0f, ELIG_TH = 0.01f;
constexpr float E_GABA = -70.0f;

__device__ __forceinline__ float clampf(float x, float lo, float hi) {
  return fminf(fmaxf(x, lo), hi);
}

struct Decays {
  float ga, gb, d, ach, ne, ca;
};

// One synapse, one timestep. Returns the synaptic current I.
__device__ __forceinline__ float step_one(
    float p, float q, float v, float r,
    float& w, float& gA, float& gN, float& gGa, float& gGb, float& tr,
    float& D, float& A, float& NEl, float& Ca, const Decays& dc) {
  const bool spk = p > 1e-3f;
  // eligibility trace
  tr = clampf((p > 0.0f) ? (tr * TRACE_DECAY + 0.1f * p) : tr, 0.0f, 1.0f);
  // conductances
  gA = clampf(gA + (spk ? 0.5f * p : 0.0f), 0.0f, 2.0f);
  gN = clampf(gN + (spk ? 0.3f * p : 0.0f), 0.0f, 1.0f);
  gGa = clampf(gGa * dc.ga + (spk ? 0.2f * p : 0.0f), 0.0f, 1.0f);
  gGb = clampf(gGb * dc.gb + (spk ? 0.1f * p : 0.0f), 0.0f, 0.5f);
  // neuromodulators
  D = D * dc.d + ((fabsf(r) > 0.01f) ? 0.5f * clampf(r, 0.0f, 2.0f) : 0.0f);
  A = A * dc.ach + ((tr > 0.1f) ? 0.2f * tr : 0.0f);
  NEl = NEl * dc.ne;
  // astrocyte
  Ca = clampf(Ca * dc.ca + ALPHA_CA * p * q, 0.0f, 2.0f);
  const float M = clampf(1.0f + BETA_ASTRO * Ca, 0.5f, 2.0f);
  // three-factor weight update
  const float neuromod = ALPHA_D * (D - 1.0f) + BETA_ACH * (A - 1.0f) +
                         GAMMA_NE * (NEl - 1.0f);
  const float dw = BASE_LR * tr * neuromod * M;
  w = clampf(w + ((tr > ELIG_TH) ? dw : 0.0f), W_MIN, W_MAX);
  // current with NMDA Mg2+ block
  const float mg = 1.0f / (1.0f + __expf(-0.062f * v) * (1.0f / 3.57f));
  const float i_exc = (gA + gN * mg) * (0.0f - v);
  const float i_inh = (gGa + gGb) * (E_GABA - v);
  return w * M * (i_exc + i_inh);
}

__device__ __forceinline__ Decays make_decays(float dt_ms) {
  Decays dc;
  dc.ga = __expf(-dt_ms / TAU_GABA_A);
  dc.gb = __expf(-dt_ms / TAU_GABA_B);
  dc.d = __expf(-dt_ms / TAU_D);
  dc.ach = __expf(-dt_ms / TAU_ACH);
  dc.ne = __expf(-dt_ms / TAU_NE);
  dc.ca = __expf(-dt_ms / TAU_CA);
  return dc;
}

__global__ __launch_bounds__(256) void synapse_vec4(
    const float4* __restrict__ pre, const float4* __restrict__ post,
    const float4* __restrict__ vpost, const float4* __restrict__ rew,
    const float4* __restrict__ w0, const float4* __restrict__ gA0,
    const float4* __restrict__ gN0, const float4* __restrict__ gGa0,
    const float4* __restrict__ gGb0, const float4* __restrict__ tr0,
    const float4* __restrict__ D0, const float4* __restrict__ A0,
    const float4* __restrict__ NE0, const float4* __restrict__ Ca0,
    const float* __restrict__ dtp, float4* __restrict__ out, int n4, int T) {
  const int idx = blockIdx.x * blockDim.x + threadIdx.x;
  if (idx >= n4) return;

  const Decays dc = make_decays(dtp[0] * 1000.0f);

  float4 wv = w0[idx], gAv = gA0[idx], gNv = gN0[idx];
  float4 gGav = gGa0[idx], gGbv = gGb0[idx], trv = tr0[idx];
  float4 Dv = D0[idx], Av = A0[idx], NEv = NE0[idx], Cav = Ca0[idx];

  // prefetch t=0
  float4 p = pre[idx], q = post[idx], v = vpost[idx], r = rew[idx];

  for (int t = 0; t < T; ++t) {
    // prefetch next timestep's rows (last iter re-reads the last row; L2-hit)
    const size_t on = (size_t)((t + 1 < T) ? t + 1 : t) * n4 + idx;
    const float4 pn = pre[on], qn = post[on], vn = vpost[on], rn = rew[on];

    float4 I;
    I.x = step_one(p.x, q.x, v.x, r.x, wv.x, gAv.x, gNv.x, gGav.x, gGbv.x,
                   trv.x, Dv.x, Av.x, NEv.x, Cav.x, dc);
    I.y = step_one(p.y, q.y, v.y, r.y, wv.y, gAv.y, gNv.y, gGav.y, gGbv.y,
                   trv.y, Dv.y, Av.y, NEv.y, Cav.y, dc);
    I.z = step_one(p.z, q.z, v.z, r.z, wv.z, gAv.z, gNv.z, gGav.z, gGbv.z,
                   trv.z, Dv.z, Av.z, NEv.z, Cav.z, dc);
    I.w = step_one(p.w, q.w, v.w, r.w, wv.w, gAv.w, gNv.w, gGav.w, gGbv.w,
                   trv.w, Dv.w, Av.w, NEv.w, Cav.w, dc);
    out[(size_t)t * n4 + idx] = I;

    p = pn; q = qn; v = vn; r = rn;
  }
}

// Scalar fallback for N not divisible by 4 (not expected for this problem).
__global__ __launch_bounds__(256) void synapse_scalar(
    const float* __restrict__ pre, const float* __restrict__ post,
    const float* __restrict__ vpost, const float* __restrict__ rew,
    const float* __restrict__ w0, const float* __restrict__ gA0,
    const float* __restrict__ gN0, const float* __restrict__ gGa0,
    const float* __restrict__ gGb0, const float* __restrict__ tr0,
    const float* __restrict__ D0, const float* __restrict__ A0,
    const float* __restrict__ NE0, const float* __restrict__ Ca0,
    const float* __restrict__ dtp, float* __restrict__ out, int N, int T) {
  const int i = blockIdx.x * blockDim.x + threadIdx.x;
  if (i >= N) return;
  const Decays dc = make_decays(dtp[0] * 1000.0f);
  float w = w0[i], gA = gA0[i], gN = gN0[i], gGa = gGa0[i], gGb = gGb0[i];
  float tr = tr0[i], D = D0[i], A = A0[i], NEl = NE0[i], Ca = Ca0[i];
  for (int t = 0; t < T; ++t) {
    const size_t o = (size_t)t * N + i;
    out[o] = step_one(pre[o], post[o], vpost[o], rew[o], w, gA, gN, gGa, gGb,
                      tr, D, A, NEl, Ca, dc);
  }
}

}  // namespace

extern "C" void kernel_launch(void* const* d_in, const int* in_sizes, int n_in,
                              void* d_out, int out_size, void* d_ws,
                              size_t ws_size, hipStream_t stream) {
  const float* pre = (const float*)d_in[0];
  const float* post = (const float*)d_in[1];
  // d_in[2] = pre_voltage: never read by the reference step.
  const float* vpost = (const float*)d_in[3];
  const float* rew = (const float*)d_in[4];
  const float* w = (const float*)d_in[5];
  const float* gA = (const float*)d_in[6];
  const float* gN = (const float*)d_in[7];
  const float* gGa = (const float*)d_in[8];
  const float* gGb = (const float*)d_in[9];
  const float* tr = (const float*)d_in[10];
  const float* D = (const float*)d_in[11];
  const float* A = (const float*)d_in[12];
  const float* NE = (const float*)d_in[13];
  const float* Ca = (const float*)d_in[14];
  // d_in[15] = astro_mod: overwritten from Ca before first read -> dead.
  const float* dt = (const float*)d_in[16];

  const int N = in_sizes[5];
  const int T = in_sizes[0] / N;
  float* out = (float*)d_out;

  if ((N & 3) == 0) {
    const int n4 = N >> 2;
    dim3 block(256), grid((n4 + 255) / 256);
    hipLaunchKernelGGL(synapse_vec4, grid, block, 0, stream,
                       (const float4*)pre, (const float4*)post,
                       (const float4*)vpost, (const float4*)rew,
                       (const float4*)w, (const float4*)gA, (const float4*)gN,
                       (const float4*)gGa, (const float4*)gGb,
                       (const float4*)tr, (const float4*)D, (const float4*)A,
                       (const float4*)NE, (const float4*)Ca, dt, (float4*)out,
                       n4, T);
  } else {
    dim3 block(256), grid((N + 255) / 256);
    hipLaunchKernelGGL(synapse_scalar, grid, block, 0, stream, pre, post,
                       vpost, rew, w, gA, gN, gGa, gGb, tr, D, A, NE, Ca, dt,
                       out, N, T);
  }
}